// Round 11
// baseline (102.847 us; speedup 1.0000x reference)
//
#include <hip/hip_runtime.h>
#include <float.h>

#define BB 2
#define CC 32
#define HH 96
#define WW 128
#define HW (HH*WW)           // 12288
#define BC (BB*CC)           // 64
#define NPLANE (BC*HW)       // 786432
#define EPSF 1e-6f
#define LOG2E 1.4426950408889634f

// ---- workspace layout (float offsets) ----
#define QR_OFF 0                               // [B*C][H] query row sums
#define QC_OFF (QR_OFF + BC*HH)                // [B*C][W] query col sums
#define QS_OFF (QC_OFF + BC*WW)                // [B*C]    query totals
#define KR_OFF (QS_OFF + BC)                   // [B*C][H] key row sums
#define KC_OFF (KR_OFF + BC*HH)                // [B*C][W] key col sums
#define KS_OFF (KC_OFF + BC*WW)                // [B*C]    key totals
// per-(c0,plane) packed record (vb = c0*BC + plane), RECSZ floats, DE-INTERLEAVED:
//   [0:96)     m_r ×log2e    [96:192)  m_c ×log2e
//   [192:320)  n_r           [320:448) n_c
//   [448:832)  R4 [h][4]     [832:1344) C4 [w][4]
#define REC_OFF (KS_OFF + BC)                  // == 28800
#define RECSZ 1344
#define BMX_OFF (REC_OFF + CC*BC*RECSZ)        // [2048][4] per-block term maxes (k3 out)
#define BSX_OFF (BMX_OFF + CC*BC*4)            // [1536]    per-block smax (k4 out)
#define PZ_OFF (BSX_OFF + 1536)                // [NPLANE]  partial z (cg=1)
// total = PZ_OFF + NPLANE ≈ 14.3 MB

__device__ __forceinline__ float rcpf(float x) { return __builtin_amdgcn_rcpf(x); }
__device__ __forceinline__ float e2(float x) { return __builtin_amdgcn_exp2f(x); }

typedef _Float16 h2v __attribute__((ext_vector_type(2)));
__device__ __forceinline__ unsigned pkrtz_u(float a, float b) {
  return __builtin_bit_cast(unsigned, __builtin_amdgcn_cvt_pkrtz(a, b));
}
__device__ __forceinline__ unsigned pk_add(unsigned a, unsigned b) {
  unsigned d; asm("v_pk_add_f16 %0, %1, %2" : "=v"(d) : "v"(a), "v"(b)); return d;
}
__device__ __forceinline__ unsigned pk_mul(unsigned a, unsigned b) {
  unsigned d; asm("v_pk_mul_f16 %0, %1, %2" : "=v"(d) : "v"(a), "v"(b)); return d;
}
__device__ __forceinline__ unsigned pk_max(unsigned a, unsigned b) {
  unsigned d; asm("v_pk_max_f16 %0, %1, %2" : "=v"(d) : "v"(a), "v"(b)); return d;
}
__device__ __forceinline__ float dot2acc(unsigned u, float acc) {
#if __has_builtin(__builtin_amdgcn_fdot2)
  h2v a = __builtin_bit_cast(h2v, u);
  h2v one = {(_Float16)1.0f, (_Float16)1.0f};
  return __builtin_amdgcn_fdot2(a, one, acc, false);
#else
  float lo = (float)__builtin_bit_cast(_Float16, (unsigned short)(u & 0xffff));
  float hi = (float)__builtin_bit_cast(_Float16, (unsigned short)(u >> 16));
  return acc + lo + hi;
#endif
}
__device__ __forceinline__ float h2max_f(unsigned u) {
  float lo = (float)__builtin_bit_cast(_Float16, (unsigned short)(u & 0xffff));
  float hi = (float)__builtin_bit_cast(_Float16, (unsigned short)(u >> 16));
  return fmaxf(lo, hi);
}

__device__ __forceinline__ float blkmax4(float v) {
  __shared__ float sred[4];
  #pragma unroll
  for (int o = 32; o > 0; o >>= 1) v = fmaxf(v, __shfl_xor(v, o, 64));
  if ((threadIdx.x & 63) == 0) sred[threadIdx.x >> 6] = v;
  __syncthreads();
  float r = fmaxf(fmaxf(sred[0], sred[1]), fmaxf(sred[2], sred[3]));
  __syncthreads();
  return r;
}

// ---------------- K1: per-plane row/col/total sums (queries and keys) ----------------
__global__ __launch_bounds__(256) void k1_plane_sums(const float* __restrict__ q,
                                                     const float* __restrict__ k,
                                                     float* __restrict__ ws) {
  int pb = blockIdx.x;
  int plane = pb & (BC - 1);
  const float* src = (pb < BC ? q : k) + (size_t)plane * HW;
  float* rowO = ws + (pb < BC ? QR_OFF : KR_OFF) + plane * HH;
  float* colO = ws + (pb < BC ? QC_OFF : KC_OFF) + plane * WW;
  float* totO = ws + (pb < BC ? QS_OFF : KS_OFF) + plane;
  __shared__ float cp[4 * WW];
  __shared__ float rsh[HH];
  __shared__ float wtot[2];
  int tid = threadIdx.x;
  int u = tid >> 6, l = tid & 63;
  float csum0 = 0.f, csum1 = 0.f;
  #pragma unroll 4
  for (int r = 0; r < 24; ++r) {
    int h = u * 24 + r;
    float v0 = src[h * WW + l];
    float v1 = src[h * WW + l + 64];
    csum0 += v0; csum1 += v1;
    float rs = v0 + v1;
    #pragma unroll
    for (int o = 1; o < 64; o <<= 1) rs += __shfl_xor(rs, o, 64);
    if (l == 0) { rowO[h] = rs; rsh[h] = rs; }
  }
  cp[u * WW + l] = csum0;
  cp[u * WW + l + 64] = csum1;
  __syncthreads();
  if (tid < WW) colO[tid] = cp[tid] + cp[WW + tid] + cp[2 * WW + tid] + cp[3 * WW + tid];
  float tv = (tid < HH) ? rsh[tid] : 0.f;
  if (tid < 128) {
    #pragma unroll
    for (int o = 1; o < 64; o <<= 1) tv += __shfl_xor(tv, o, 64);
    if ((tid & 63) == 0) wtot[tid >> 6] = tv;
  }
  __syncthreads();
  if (tid == 0) *totO = wtot[0] + wtot[1];
}

// ---------------- K2: min-max-normalized vectors into de-interleaved record fields ----------------
__device__ __forceinline__ float k2_raw(const float* __restrict__ ws, int type, int c0, int i, int L) {
  int bc = i / L, x = i - bc * L;
  int b = bc >> 5;
  if (type == 0) return ws[QS_OFF + b * CC + c0] * ws[KR_OFF + bc * HH + x] + HH * EPSF;
  if (type == 1) return ws[QR_OFF + (b * CC + c0) * HH + x] * ws[KS_OFF + bc] + HH * EPSF;
  if (type == 2) return ws[QS_OFF + b * CC + c0] * ws[KC_OFF + bc * WW + x] + WW * EPSF;
  return ws[QC_OFF + (b * CC + c0) * WW + x] * ws[KS_OFF + bc] + WW * EPSF;
}

__global__ __launch_bounds__(256) void k2_vec_norm(float* __restrict__ ws) {
  int c0 = blockIdx.x >> 2, type = blockIdx.x & 3;
  int L = (type < 2) ? HH : WW;
  int N = BC * L;
  int tid = threadIdx.x;
  float mx = -FLT_MAX, mn = FLT_MAX;
  for (int i = tid; i < N; i += 256) {
    float v = k2_raw(ws, type, c0, i, L);
    mx = fmaxf(mx, v); mn = fminf(mn, v);
  }
  mx = blkmax4(mx);
  mn = -blkmax4(-mn);
  float scale = rcpf(mx - mn);
  float fold = (type < 2) ? LOG2E : 1.0f;
  int fieldbase = (type == 0) ? 0 : (type == 1) ? 96 : (type == 2) ? 192 : 320;
  for (int i = tid; i < N; i += 256) {
    int bc = i / L, x = i - bc * L;
    float v = k2_raw(ws, type, c0, i, L);
    ws[REC_OFF + (size_t)(c0 * BC + bc) * RECSZ + fieldbase + x] =
        (2.0f + (v - mn) * scale) * fold;
  }
}

// ---------------- K3: one block per (vb,t); e once in fp16 LDS; fused row-sum+max pass ----------------
#define EPH 136                        // halves per row (272B, 16B-aligned)
__global__ __launch_bounds__(256) void k3_rc(float* __restrict__ ws) {
  int g = blockIdx.x;                  // vb*4 + t
  int vb = g >> 2, t = g & 3;
  float* rec = ws + REC_OFF + (size_t)vb * RECSZ;
  int tid = threadIdx.x;
  int u = tid >> 6, l = tid & 63;
  __shared__ __align__(16) unsigned short eh[HH * EPH];   // 26112 B fp16 e
  __shared__ __align__(16) float mncp[512];               // m[0:96] n[96:224]; later cpart[4][128]
  __shared__ __align__(16) unsigned short rch[128];       // fp16 4096*rC
  __shared__ float wmx[3];
  const float* mv = rec + (t >> 1) * 96;
  const float* nv = rec + 192 + (t & 1) * 128;
  if (tid < 224) mncp[tid] = (tid < 96) ? mv[tid] : nv[tid - 96];
  __syncthreads();                                        // B1
  // ---- pass A: wave u owns rows 24u..24u+23; lane owns cols 2l,2l+1. e once. ----
  float n0 = mncp[96 + 2 * l], n1 = mncp[96 + 2 * l + 1];
  float cs0 = 0.f, cs1 = 0.f;
  #pragma unroll 6
  for (int r = 0; r < 24; ++r) {
    int h = u * 24 + r;
    float m = mncp[h];
    float e0 = e2(m * n0);
    float e1 = e2(m * n1);
    cs0 += e0; cs1 += e1;
    *(unsigned*)&eh[h * EPH + 2 * l] = pkrtz_u(e0, e1);
  }
  __syncthreads();                                        // B2 (mn reads done, eh complete)
  mncp[u * 128 + 2 * l] = cs0;
  mncp[u * 128 + 2 * l + 1] = cs1;
  __syncthreads();                                        // B3 (cpart ready)
  if (tid < 64) {                      // lane owns cols 2tid, 2tid+1
    int w0 = 2 * tid, w1 = w0 + 1;
    float rc0 = rcpf(mncp[w0] + mncp[128 + w0] + mncp[256 + w0] + mncp[384 + w0]);
    float rc1 = rcpf(mncp[w1] + mncp[128 + w1] + mncp[256 + w1] + mncp[384 + w1]);
    rec[832 + 4 * w0 + t] = rc0;
    rec[832 + 4 * w1 + t] = rc1;
    ((unsigned*)rch)[tid] = pkrtz_u(rc0 * 4096.f, rc1 * 4096.f);
  }
  __syncthreads();                                        // B4 (rch ready)
  // ---- fused pass B+C: lanes 0-191 own half-rows; e loaded ONCE into regs ----
  float mx = 0.f;
  if (tid < 192) {
    int row = tid >> 1, hf = tid & 1;
    const uint4* ep = (const uint4*)&eh[row * EPH + hf * 64];
    uint4 ev[8];
    #pragma unroll
    for (int j = 0; j < 8; ++j) ev[j] = ep[j];
    float sa = 0.f, sb = 0.f, sc1 = 0.f, sd = 0.f;
    #pragma unroll
    for (int j = 0; j < 8; ++j) {
      sa = dot2acc(ev[j].x, sa); sb = dot2acc(ev[j].y, sb);
      sc1 = dot2acc(ev[j].z, sc1); sd = dot2acc(ev[j].w, sd);
    }
    float s = (sa + sb) + (sc1 + sd);
    s += __shfl_xor(s, 1, 64);         // partner has other w-half of same row
    float rr = rcpf(s);
    if (hf == 0) rec[448 + 4 * row + t] = rr;
    unsigned rr2 = pkrtz_u(rr * 4096.f, rr * 4096.f);
    const uint4* cp2 = (const uint4*)&rch[hf * 64];   // 2 addrs/wave -> broadcast
    unsigned mxa = 0, mxb = 0, mxc = 0, mxd = 0;
    #pragma unroll
    for (int j = 0; j < 8; ++j) {
      uint4 cv = cp2[j];
      mxa = pk_max(mxa, pk_mul(ev[j].x, pk_add(cv.x, rr2)));
      mxb = pk_max(mxb, pk_mul(ev[j].y, pk_add(cv.y, rr2)));
      mxc = pk_max(mxc, pk_mul(ev[j].z, pk_add(cv.z, rr2)));
      mxd = pk_max(mxd, pk_mul(ev[j].w, pk_add(cv.w, rr2)));
    }
    unsigned mxu = pk_max(pk_max(mxa, mxb), pk_max(mxc, mxd));
    mx = h2max_f(mxu) * (1.0f / 4096.f);
    #pragma unroll
    for (int o = 1; o < 64; o <<= 1) mx = fmaxf(mx, __shfl_xor(mx, o, 64));
    if ((tid & 63) == 0) wmx[tid >> 6] = mx;
  }
  __syncthreads();                                        // B5
  if (tid == 0) ws[BMX_OFF + vb * 4 + t] = fmaxf(fmaxf(wmx[0], wmx[1]), wmx[2]);
}

// ---------------- K4: c-split ×2, ELEMS=4, packed-pair LDS; partial z; pre-scaled R4/C4 ----------------
#define ELEMS 4
#define TILES 12                       // 256*ELEMS*TILES == HW
#define NCG 2
#define CG (CC/NCG)                    // 16
#define GRP 4
__global__ __launch_bounds__(256) void k4_score(const float* __restrict__ values,
                                                float* __restrict__ ws,
                                                float* __restrict__ out) {
  int bx = blockIdx.x;                 // (cb*TILES + tile)*2 + cg  -> 1536 blocks
  int cg = bx & 1, bxx = bx >> 1;
  int tile = bxx % TILES;
  int cb = bxx / TILES;
  int b = cb & 1, c0 = cb >> 1;
  int tid = threadIdx.x;
  int base = tile * 1024;              // 8 rows per block
  int w = tid & 127, r0 = tid >> 7;
  __shared__ __align__(16) float n2S[GRP][256];   // [ch][ (nr,nc) pairs ]
  __shared__ __align__(16) float c4S[GRP][512];   // [ch][ C4×im flat ]
  __shared__ __align__(16) float mrf[CG * 48];    // [ch][ (mR,mC) pairs 0:16 | r4×im 16:48 ]
  __shared__ float s44[4][4];
  const float* rec0 = ws + REC_OFF + (size_t)(c0 * BC + b * CC) * RECSZ;
  const float* recg = rec0 + (size_t)(cg * CG) * RECSZ;
  // --- prologue: BMX reduce + mrf pair-stage (own 16 channels) + v loads ---
  float bm = ws[BMX_OFF + c0 * 256 + tid];
  #pragma unroll
  for (int o = 4; o <= 32; o <<= 1) bm = fmaxf(bm, __shfl_xor(bm, o, 64));
  if ((tid & 63) < 4) s44[tid >> 6][tid & 3] = bm;
  if (tid < 160) {                     // 16 ch × 10 slots
    int ch = tid / 10, f = tid - 10 * (tid / 10);
    const float* rsrc = recg + (size_t)ch * RECSZ;
    if (f < 2) {                       // m pairs: 4 rows per slot
      float4 a = *(const float4*)(rsrc + tile * 8 + 4 * f);
      float4 bb = *(const float4*)(rsrc + 96 + tile * 8 + 4 * f);
      float* d = &mrf[ch * 48 + 8 * f];
      d[0] = a.x; d[1] = bb.x; d[2] = a.y; d[3] = bb.y;
      d[4] = a.z; d[5] = bb.z; d[6] = a.w; d[7] = bb.w;
    } else {                           // r4 rows (scaled later)
      int ff = f - 2;                  // 0..7
      *(float4*)&mrf[ch * 48 + 16 + 4 * ff] = *(const float4*)(rsrc + 448 + 32 * tile + 4 * ff);
    }
  }
  const float* vsrc0 = values + (size_t)(b * CC) * HW + base + tid;
  float vr[ELEMS];
  #pragma unroll
  for (int j = 0; j < ELEMS; ++j) vr[j] = vsrc0[(size_t)(cg * CG) * HW + 256 * j];
  __syncthreads();                     // B1: s44 + raw mrf visible
  float im0 = rcpf(fmaxf(fmaxf(s44[0][0], s44[1][0]), fmaxf(s44[2][0], s44[3][0])));
  float im1 = rcpf(fmaxf(fmaxf(s44[0][1], s44[1][1]), fmaxf(s44[2][1], s44[3][1])));
  float im2 = rcpf(fmaxf(fmaxf(s44[0][2], s44[1][2]), fmaxf(s44[2][2], s44[3][2])));
  float im3 = rcpf(fmaxf(fmaxf(s44[0][3], s44[1][3]), fmaxf(s44[2][3], s44[3][3])));
  // scale mrf r4 region in place (distinct entries per thread)
  for (int i = tid; i < CG * 32; i += 256) {
    int ch = i >> 5, kk = i & 31, tt = kk & 3;
    float sel = tt == 0 ? im0 : tt == 1 ? im1 : tt == 2 ? im2 : im3;
    mrf[ch * 48 + 16 + kk] *= sel;
  }
  // stage group 0 (n pairs + c4 scaled)
  #pragma unroll
  for (int i = tid; i < GRP * 192; i += 256) {
    int chl = i / 192, rem = i - 192 * (i / 192);
    const float* rsrc = recg + (size_t)chl * RECSZ;
    if (rem < 64) {
      float2 a = *(const float2*)(rsrc + 192 + 2 * rem);
      float2 bb = *(const float2*)(rsrc + 320 + 2 * rem);
      *(float4*)&n2S[chl][4 * rem] = float4{a.x, bb.x, a.y, bb.y};
    } else {
      float4 g4 = *(const float4*)(rsrc + 832 + 4 * (rem - 64));
      g4.x *= im0; g4.y *= im1; g4.z *= im2; g4.w *= im3;
      *(float4*)&c4S[chl][4 * (rem - 64)] = g4;
    }
  }
  __syncthreads();                     // B2: group 0 + scaled mrf visible
  float U[ELEMS] = {0.f, 0.f, 0.f, 0.f};
  float smaxl = 0.f;
  for (int ci = 0; ci < CG; ++ci) {
    if ((ci & (GRP - 1)) == 0 && ci) { // re-stage group ci/GRP
      __syncthreads();
      #pragma unroll
      for (int i = tid; i < GRP * 192; i += 256) {
        int chl = i / 192, rem = i - 192 * (i / 192);
        const float* rsrc = recg + (size_t)(ci + chl) * RECSZ;
        if (rem < 64) {
          float2 a = *(const float2*)(rsrc + 192 + 2 * rem);
          float2 bb = *(const float2*)(rsrc + 320 + 2 * rem);
          *(float4*)&n2S[chl][4 * rem] = float4{a.x, bb.x, a.y, bb.y};
        } else {
          float4 g4 = *(const float4*)(rsrc + 832 + 4 * (rem - 64));
          g4.x *= im0; g4.y *= im1; g4.z *= im2; g4.w *= im3;
          *(float4*)&c4S[chl][4 * (rem - 64)] = g4;
        }
      }
      __syncthreads();
    }
    float nv[ELEMS];
    if (ci + 1 < CG) {                 // prefetch next channel's values
      #pragma unroll
      for (int j = 0; j < ELEMS; ++j)
        nv[j] = vsrc0[(size_t)(cg * CG + ci + 1) * HW + 256 * j];
    }
    int cl = ci & (GRP - 1);
    float2 n2 = *(const float2*)&n2S[cl][2 * w];
    float4 c4 = *(const float4*)&c4S[cl][4 * w];
    const float* mc = &mrf[ci * 48];
    #pragma unroll
    for (int j = 0; j < ELEMS; ++j) {
      int r = r0 + 2 * j;
      float2 m2 = *(const float2*)&mc[2 * r];
      float4 r4 = *(const float4*)&mc[16 + 4 * r];
      float sc = e2(m2.x * n2.x) * (r4.x + c4.x) + e2(m2.x * n2.y) * (r4.y + c4.y)
               + e2(m2.y * n2.x) * (r4.z + c4.z) + e2(m2.y * n2.y) * (r4.w + c4.w);
      smaxl = fmaxf(smaxl, sc);
      U[j] += sc * vr[j];
    }
    if (ci + 1 < CG) {
      #pragma unroll
      for (int j = 0; j < ELEMS; ++j) vr[j] = nv[j];
    }
  }
  float* zt = (cg == 0 ? out : ws + PZ_OFF) + (size_t)(b * CC + c0) * HW + base + tid;
  #pragma unroll
  for (int j = 0; j < ELEMS; ++j) zt[256 * j] = U[j];
  smaxl = blkmax4(smaxl);
  if (tid == 0) ws[BSX_OFF + bx] = smaxl;
}

// ---------------- K5: z combine+scale (512 blocks) + score recompute c0=31 (128 blocks) ----------------
#define K5_ZB (BC * 8)                 // 512
__global__ __launch_bounds__(256) void k5_final(float* __restrict__ out,
                                                const float* __restrict__ ws) {
  int bx = blockIdx.x;
  int tid = threadIdx.x;
  if (bx < K5_ZB) {
    int p = bx >> 3, sub = bx & 7;     // p = b*CC + c0 z-plane
    int c0 = p & (CC - 1);
    __shared__ float sm;
    if (tid < 64) {
      float a = (tid < 48) ? ws[BSX_OFF + c0 * 48 + tid] : 0.f;
      #pragma unroll
      for (int o = 1; o < 64; o <<= 1) a = fmaxf(a, __shfl_xor(a, o, 64));
      if (tid == 0) sm = a;
    }
    __syncthreads();
    float ism = rcpf(sm);
    const float* pz = ws + PZ_OFF;
    int off = p * HW + sub * 1536 + tid;
    #pragma unroll
    for (int j = 0; j < 6; ++j) {
      int i = off + 256 * j;
      out[i] = (out[i] + pz[i]) * ism;
    }
  } else {
    int sp = bx - K5_ZB;               // 128 blocks: plane = sp>>1, half = sp&1
    int plane = sp >> 1, half = sp & 1;
    const float* rec = ws + REC_OFF + (size_t)((CC - 1) * BC + plane) * RECSZ;
    __shared__ __align__(16) float R[RECSZ];
    __shared__ float s44[4][4];
    __shared__ float sm;
    for (int i = tid; i < RECSZ / 4; i += 256) ((float4*)R)[i] = ((const float4*)rec)[i];
    float bm = ws[BMX_OFF + (CC - 1) * 256 + tid];
    #pragma unroll
    for (int o = 4; o <= 32; o <<= 1) bm = fmaxf(bm, __shfl_xor(bm, o, 64));
    if ((tid & 63) < 4) s44[tid >> 6][tid & 3] = bm;
    if (tid < 64) {
      float a = (tid < 48) ? ws[BSX_OFF + (CC - 1) * 48 + tid] : 0.f;
      #pragma unroll
      for (int o = 1; o < 64; o <<= 1) a = fmaxf(a, __shfl_xor(a, o, 64));
      if (tid == 0) sm = a;
    }
    __syncthreads();
    float im0 = rcpf(fmaxf(fmaxf(s44[0][0], s44[1][0]), fmaxf(s44[2][0], s44[3][0])));
    float im1 = rcpf(fmaxf(fmaxf(s44[0][1], s44[1][1]), fmaxf(s44[2][1], s44[3][1])));
    float im2 = rcpf(fmaxf(fmaxf(s44[0][2], s44[1][2]), fmaxf(s44[2][2], s44[3][2])));
    float im3 = rcpf(fmaxf(fmaxf(s44[0][3], s44[1][3]), fmaxf(s44[2][3], s44[3][3])));
    float isml = rcpf(sm);
    float* sout = out + (size_t)NPLANE + (size_t)plane * HW + half * 6144;
    #pragma unroll 4
    for (int e = tid; e < 6144; e += 256) {
      int idx = half * 6144 + e;
      int h = idx >> 7, ww = idx & 127;
      float mR = R[h], mC = R[96 + h];
      float nr = R[192 + ww], nc = R[320 + ww];
      float4 r4 = *(const float4*)&R[448 + 4 * h];
      float4 c4 = *(const float4*)&R[832 + 4 * ww];
      float A0 = c4.x * im0, A1 = c4.y * im1, A2 = c4.z * im2, A3 = c4.w * im3;
      float sc = e2(mR * nr) * fmaf(r4.x, im0, A0) + e2(mR * nc) * fmaf(r4.y, im1, A1)
               + e2(mC * nr) * fmaf(r4.z, im2, A2) + e2(mC * nc) * fmaf(r4.w, im3, A3);
      sout[e] = sc * isml;
    }
  }
}

extern "C" void kernel_launch(void* const* d_in, const int* in_sizes, int n_in,
                              void* d_out, int out_size, void* d_ws, size_t ws_size,
                              hipStream_t stream) {
  const float* q = (const float*)d_in[0];
  const float* k = (const float*)d_in[1];
  const float* v = (const float*)d_in[2];
  float* out = (float*)d_out;
  float* ws = (float*)d_ws;
  k1_plane_sums<<<2 * BC, 256, 0, stream>>>(q, k, ws);
  k2_vec_norm<<<CC * 4, 256, 0, stream>>>(ws);
  k3_rc<<<CC * BC * 4, 256, 0, stream>>>(ws);
  k4_score<<<CC * BB * TILES * NCG, 256, 0, stream>>>(v, ws, out);
  k5_final<<<K5_ZB + 128, 256, 0, stream>>>(out, ws);
}

// Round 12
// 98.291 us; speedup vs baseline: 1.0464x; 1.0464x over previous
//
#include <hip/hip_runtime.h>
#include <float.h>

#define BB 2
#define CC 32
#define HH 96
#define WW 128
#define HW (HH*WW)           // 12288
#define BC (BB*CC)           // 64
#define NPLANE (BC*HW)       // 786432
#define EPSF 1e-6f
#define LOG2E 1.4426950408889634f

// ---- workspace layout (float offsets) ----
#define QR_OFF 0                               // [B*C][H] query row sums
#define QC_OFF (QR_OFF + BC*HH)                // [B*C][W] query col sums
#define QS_OFF (QC_OFF + BC*WW)                // [B*C]    query totals
#define KR_OFF (QS_OFF + BC)                   // [B*C][H] key row sums
#define KC_OFF (KR_OFF + BC*HH)                // [B*C][W] key col sums
#define KS_OFF (KC_OFF + BC*WW)                // [B*C]    key totals
// per-(c0,plane) packed record (vb = c0*BC + plane), RECSZ floats, DE-INTERLEAVED:
//   [0:96)     m_r ×log2e    [96:192)  m_c ×log2e
//   [192:320)  n_r           [320:448) n_c
//   [448:832)  R4 [h][4]     [832:1344) C4 [w][4]
#define REC_OFF (KS_OFF + BC)                  // == 28800
#define RECSZ 1344
#define BMX_OFF (REC_OFF + CC*BC*RECSZ)        // [2048][4] per-block term maxes (k3 out)
#define BSX_OFF (BMX_OFF + CC*BC*4)            // [1536]    per-block smax (k4 out)
#define PZ_OFF (BSX_OFF + 1536)                // [NPLANE]  partial z (cg=1)
// total = PZ_OFF + NPLANE ≈ 14.3 MB

__device__ __forceinline__ float rcpf(float x) { return __builtin_amdgcn_rcpf(x); }
__device__ __forceinline__ float e2(float x) { return __builtin_amdgcn_exp2f(x); }

typedef _Float16 h2v __attribute__((ext_vector_type(2)));
__device__ __forceinline__ unsigned pkrtz_u(float a, float b) {
  return __builtin_bit_cast(unsigned, __builtin_amdgcn_cvt_pkrtz(a, b));
}
__device__ __forceinline__ unsigned pk_add(unsigned a, unsigned b) {
  unsigned d; asm("v_pk_add_f16 %0, %1, %2" : "=v"(d) : "v"(a), "v"(b)); return d;
}
__device__ __forceinline__ unsigned pk_mul(unsigned a, unsigned b) {
  unsigned d; asm("v_pk_mul_f16 %0, %1, %2" : "=v"(d) : "v"(a), "v"(b)); return d;
}
__device__ __forceinline__ unsigned pk_max(unsigned a, unsigned b) {
  unsigned d; asm("v_pk_max_f16 %0, %1, %2" : "=v"(d) : "v"(a), "v"(b)); return d;
}
__device__ __forceinline__ float dot2acc(unsigned u, float acc) {
#if __has_builtin(__builtin_amdgcn_fdot2)
  h2v a = __builtin_bit_cast(h2v, u);
  h2v one = {(_Float16)1.0f, (_Float16)1.0f};
  return __builtin_amdgcn_fdot2(a, one, acc, false);
#else
  float lo = (float)__builtin_bit_cast(_Float16, (unsigned short)(u & 0xffff));
  float hi = (float)__builtin_bit_cast(_Float16, (unsigned short)(u >> 16));
  return acc + lo + hi;
#endif
}
__device__ __forceinline__ float h2max_f(unsigned u) {
  float lo = (float)__builtin_bit_cast(_Float16, (unsigned short)(u & 0xffff));
  float hi = (float)__builtin_bit_cast(_Float16, (unsigned short)(u >> 16));
  return fmaxf(lo, hi);
}

__device__ __forceinline__ float blkmax4(float v) {
  __shared__ float sred[4];
  #pragma unroll
  for (int o = 32; o > 0; o >>= 1) v = fmaxf(v, __shfl_xor(v, o, 64));
  if ((threadIdx.x & 63) == 0) sred[threadIdx.x >> 6] = v;
  __syncthreads();
  float r = fmaxf(fmaxf(sred[0], sred[1]), fmaxf(sred[2], sred[3]));
  __syncthreads();
  return r;
}

// ---------------- K1: per-plane row/col/total sums (queries and keys) ----------------
__global__ __launch_bounds__(256) void k1_plane_sums(const float* __restrict__ q,
                                                     const float* __restrict__ k,
                                                     float* __restrict__ ws) {
  int pb = blockIdx.x;
  int plane = pb & (BC - 1);
  const float* src = (pb < BC ? q : k) + (size_t)plane * HW;
  float* rowO = ws + (pb < BC ? QR_OFF : KR_OFF) + plane * HH;
  float* colO = ws + (pb < BC ? QC_OFF : KC_OFF) + plane * WW;
  float* totO = ws + (pb < BC ? QS_OFF : KS_OFF) + plane;
  __shared__ float cp[4 * WW];
  __shared__ float rsh[HH];
  __shared__ float wtot[2];
  int tid = threadIdx.x;
  int u = tid >> 6, l = tid & 63;
  float csum0 = 0.f, csum1 = 0.f;
  #pragma unroll 4
  for (int r = 0; r < 24; ++r) {
    int h = u * 24 + r;
    float v0 = src[h * WW + l];
    float v1 = src[h * WW + l + 64];
    csum0 += v0; csum1 += v1;
    float rs = v0 + v1;
    #pragma unroll
    for (int o = 1; o < 64; o <<= 1) rs += __shfl_xor(rs, o, 64);
    if (l == 0) { rowO[h] = rs; rsh[h] = rs; }
  }
  cp[u * WW + l] = csum0;
  cp[u * WW + l + 64] = csum1;
  __syncthreads();
  if (tid < WW) colO[tid] = cp[tid] + cp[WW + tid] + cp[2 * WW + tid] + cp[3 * WW + tid];
  float tv = (tid < HH) ? rsh[tid] : 0.f;
  if (tid < 128) {
    #pragma unroll
    for (int o = 1; o < 64; o <<= 1) tv += __shfl_xor(tv, o, 64);
    if ((tid & 63) == 0) wtot[tid >> 6] = tv;
  }
  __syncthreads();
  if (tid == 0) *totO = wtot[0] + wtot[1];
}

// ---------------- K2: min-max-normalized vectors into de-interleaved record fields ----------------
__device__ __forceinline__ float k2_raw(const float* __restrict__ ws, int type, int c0, int i, int L) {
  int bc = i / L, x = i - bc * L;
  int b = bc >> 5;
  if (type == 0) return ws[QS_OFF + b * CC + c0] * ws[KR_OFF + bc * HH + x] + HH * EPSF;
  if (type == 1) return ws[QR_OFF + (b * CC + c0) * HH + x] * ws[KS_OFF + bc] + HH * EPSF;
  if (type == 2) return ws[QS_OFF + b * CC + c0] * ws[KC_OFF + bc * WW + x] + WW * EPSF;
  return ws[QC_OFF + (b * CC + c0) * WW + x] * ws[KS_OFF + bc] + WW * EPSF;
}

__global__ __launch_bounds__(256) void k2_vec_norm(float* __restrict__ ws) {
  int c0 = blockIdx.x >> 2, type = blockIdx.x & 3;
  int L = (type < 2) ? HH : WW;
  int N = BC * L;
  int tid = threadIdx.x;
  float mx = -FLT_MAX, mn = FLT_MAX;
  for (int i = tid; i < N; i += 256) {
    float v = k2_raw(ws, type, c0, i, L);
    mx = fmaxf(mx, v); mn = fminf(mn, v);
  }
  mx = blkmax4(mx);
  mn = -blkmax4(-mn);
  float scale = rcpf(mx - mn);
  float fold = (type < 2) ? LOG2E : 1.0f;
  int fieldbase = (type == 0) ? 0 : (type == 1) ? 96 : (type == 2) ? 192 : 320;
  for (int i = tid; i < N; i += 256) {
    int bc = i / L, x = i - bc * L;
    float v = k2_raw(ws, type, c0, i, L);
    ws[REC_OFF + (size_t)(c0 * BC + bc) * RECSZ + fieldbase + x] =
        (2.0f + (v - mn) * scale) * fold;
  }
}

// ---------------- K3: one block per (vb,t); e computed ONCE, fp16 LDS; packed reduce ----------------
#define EPH 136                        // halves per row (272B, 16B-aligned)
__global__ __launch_bounds__(256) void k3_rc(float* __restrict__ ws) {
  int g = blockIdx.x;                  // vb*4 + t
  int vb = g >> 2, t = g & 3;
  float* rec = ws + REC_OFF + (size_t)vb * RECSZ;
  int tid = threadIdx.x;
  int u = tid >> 6, l = tid & 63;
  __shared__ __align__(16) unsigned short eh[HH * EPH];   // 26112 B fp16 e
  __shared__ __align__(16) float mncp[512];               // m[0:96] n[96:224]; later cpart[4][128]
  __shared__ __align__(16) unsigned short rch[128];       // fp16 4096*rC
  __shared__ float wmx[3];
  const float* mv = rec + (t >> 1) * 96;
  const float* nv = rec + 192 + (t & 1) * 128;
  if (tid < 224) mncp[tid] = (tid < 96) ? mv[tid] : nv[tid - 96];
  __syncthreads();                                        // B1
  // ---- pass A: wave u owns rows 24u..24u+23; lane owns cols 2l,2l+1. e once. ----
  float n0 = mncp[96 + 2 * l], n1 = mncp[96 + 2 * l + 1];
  float cs0 = 0.f, cs1 = 0.f;
  #pragma unroll 6
  for (int r = 0; r < 24; ++r) {
    int h = u * 24 + r;
    float m = mncp[h];
    float e0 = e2(m * n0);
    float e1 = e2(m * n1);
    cs0 += e0; cs1 += e1;
    *(unsigned*)&eh[h * EPH + 2 * l] = pkrtz_u(e0, e1);
  }
  __syncthreads();                                        // B2 (mn reads done, eh complete)
  mncp[u * 128 + 2 * l] = cs0;
  mncp[u * 128 + 2 * l + 1] = cs1;
  __syncthreads();                                        // B3 (cpart ready)
  if (tid < 64) {                      // lane owns cols 2tid, 2tid+1
    int w0 = 2 * tid, w1 = w0 + 1;
    float rc0 = rcpf(mncp[w0] + mncp[128 + w0] + mncp[256 + w0] + mncp[384 + w0]);
    float rc1 = rcpf(mncp[w1] + mncp[128 + w1] + mncp[256 + w1] + mncp[384 + w1]);
    rec[832 + 4 * w0 + t] = rc0;
    rec[832 + 4 * w1 + t] = rc1;
    ((unsigned*)rch)[tid] = pkrtz_u(rc0 * 4096.f, rc1 * 4096.f);
  }
  __syncthreads();                                        // B4 (rch ready)
  // ---- pass B+C: lanes 0-191 own half-rows (row=tid>>1, hf=tid&1) ----
  float mx = 0.f;
  if (tid < 192) {
    int row = tid >> 1, hf = tid & 1;
    const uint4* ep = (const uint4*)&eh[row * EPH + hf * 64];
    float s = 0.f;
    #pragma unroll
    for (int j = 0; j < 8; ++j) {
      uint4 ev = ep[j];
      s = dot2acc(ev.x, s); s = dot2acc(ev.y, s);
      s = dot2acc(ev.z, s); s = dot2acc(ev.w, s);
    }
    s += __shfl_xor(s, 1, 64);         // partner has other w-half of same row
    float rr = rcpf(s);
    if (hf == 0) rec[448 + 4 * row + t] = rr;
    unsigned rr2 = pkrtz_u(rr * 4096.f, rr * 4096.f);
    unsigned mxu = 0;
    const uint4* cp2 = (const uint4*)&rch[hf * 64];
    #pragma unroll
    for (int j = 0; j < 8; ++j) {
      uint4 ev = ep[j];
      uint4 cv = cp2[j];
      mxu = pk_max(mxu, pk_mul(ev.x, pk_add(cv.x, rr2)));
      mxu = pk_max(mxu, pk_mul(ev.y, pk_add(cv.y, rr2)));
      mxu = pk_max(mxu, pk_mul(ev.z, pk_add(cv.z, rr2)));
      mxu = pk_max(mxu, pk_mul(ev.w, pk_add(cv.w, rr2)));
    }
    mx = h2max_f(mxu) * (1.0f / 4096.f);
    #pragma unroll
    for (int o = 1; o < 64; o <<= 1) mx = fmaxf(mx, __shfl_xor(mx, o, 64));
    if ((tid & 63) == 0) wmx[tid >> 6] = mx;
  }
  __syncthreads();                                        // B5
  if (tid == 0) ws[BMX_OFF + vb * 4 + t] = fmaxf(fmaxf(wmx[0], wmx[1]), wmx[2]);
}

// ---------------- K4: c-split ×2, ELEMS=4, all-LDS; partial z; pre-scaled R4/C4 ----------------
#define ELEMS 4
#define TILES 12                       // 256*ELEMS*TILES == HW
#define NCG 2
#define CG (CC/NCG)                    // 16
#define GRP 4
__global__ __launch_bounds__(256) void k4_score(const float* __restrict__ values,
                                                float* __restrict__ ws,
                                                float* __restrict__ out) {
  int bx = blockIdx.x;                 // (cb*TILES + tile)*2 + cg  -> 1536 blocks
  int cg = bx & 1, bxx = bx >> 1;
  int tile = bxx % TILES;
  int cb = bxx / TILES;
  int b = cb & 1, c0 = cb >> 1;
  int tid = threadIdx.x;
  int base = tile * 1024;              // 8 rows per block
  int w = tid & 127, r0 = tid >> 7;
  __shared__ __align__(16) float nS[GRP][256];    // [ch][ nr 0:128 | nc 128:256 ]
  __shared__ __align__(16) float c4S[GRP][512];   // [ch][ C4×im flat ]
  __shared__ __align__(16) float mrf[CG * 48];    // [ch][ m_r[8] | m_c[8] | r4×im[32] ]
  __shared__ float s44[4][4];
  const float* rec0 = ws + REC_OFF + (size_t)(c0 * BC + b * CC) * RECSZ;
  const float* recg = rec0 + (size_t)(cg * CG) * RECSZ;
  // --- prologue: BMX reduce + raw mrf stage (own 16 channels) + v loads ---
  float bm = ws[BMX_OFF + c0 * 256 + tid];
  #pragma unroll
  for (int o = 4; o <= 32; o <<= 1) bm = fmaxf(bm, __shfl_xor(bm, o, 64));
  if ((tid & 63) < 4) s44[tid >> 6][tid & 3] = bm;
  if (tid < 192) {                     // 16 ch × 12 float4
    int ch = tid / 12, f = tid - 12 * (tid / 12);
    const float* rsrc = recg + (size_t)ch * RECSZ;
    int soff = (f < 2) ? tile * 8 + 4 * f
             : (f < 4) ? 96 + tile * 8 + 4 * (f - 2)
                       : 448 + 32 * tile + 4 * (f - 4);
    *(float4*)&mrf[ch * 48 + f * 4] = *(const float4*)(rsrc + soff);
  }
  const float* vsrc0 = values + (size_t)(b * CC) * HW + base + tid;
  float vr[ELEMS];
  #pragma unroll
  for (int j = 0; j < ELEMS; ++j) vr[j] = vsrc0[(size_t)(cg * CG) * HW + 256 * j];
  __syncthreads();                     // B1: s44 + raw mrf visible
  float im0 = rcpf(fmaxf(fmaxf(s44[0][0], s44[1][0]), fmaxf(s44[2][0], s44[3][0])));
  float im1 = rcpf(fmaxf(fmaxf(s44[0][1], s44[1][1]), fmaxf(s44[2][1], s44[3][1])));
  float im2 = rcpf(fmaxf(fmaxf(s44[0][2], s44[1][2]), fmaxf(s44[2][2], s44[3][2])));
  float im3 = rcpf(fmaxf(fmaxf(s44[0][3], s44[1][3]), fmaxf(s44[2][3], s44[3][3])));
  // scale mrf r4 region in place (distinct entries per thread)
  for (int i = tid; i < CG * 32; i += 256) {
    int ch = i >> 5, kk = i & 31, tt = kk & 3;
    float sel = tt == 0 ? im0 : tt == 1 ? im1 : tt == 2 ? im2 : im3;
    mrf[ch * 48 + 16 + kk] *= sel;
  }
  // stage group 0 (c4 scaled)
  #pragma unroll
  for (int i = tid; i < GRP * 192; i += 256) {
    int chl = i / 192, rem = i - 192 * (i / 192);
    const float* rsrc = recg + (size_t)chl * RECSZ;
    if (rem < 64) {
      *(float4*)&nS[chl][4 * rem] = *(const float4*)(rsrc + 192 + 4 * rem);
    } else {
      float4 g4 = *(const float4*)(rsrc + 832 + 4 * (rem - 64));
      g4.x *= im0; g4.y *= im1; g4.z *= im2; g4.w *= im3;
      *(float4*)&c4S[chl][4 * (rem - 64)] = g4;
    }
  }
  __syncthreads();                     // B2: group 0 + scaled mrf visible
  float U[ELEMS] = {0.f, 0.f, 0.f, 0.f};
  float smaxl = 0.f;
  for (int ci = 0; ci < CG; ++ci) {
    if ((ci & (GRP - 1)) == 0 && ci) { // re-stage group ci/GRP
      __syncthreads();
      #pragma unroll
      for (int i = tid; i < GRP * 192; i += 256) {
        int chl = i / 192, rem = i - 192 * (i / 192);
        const float* rsrc = recg + (size_t)(ci + chl) * RECSZ;
        if (rem < 64) {
          *(float4*)&nS[chl][4 * rem] = *(const float4*)(rsrc + 192 + 4 * rem);
        } else {
          float4 g4 = *(const float4*)(rsrc + 832 + 4 * (rem - 64));
          g4.x *= im0; g4.y *= im1; g4.z *= im2; g4.w *= im3;
          *(float4*)&c4S[chl][4 * (rem - 64)] = g4;
        }
      }
      __syncthreads();
    }
    float nv[ELEMS];
    if (ci + 1 < CG) {                 // prefetch next channel's values
      #pragma unroll
      for (int j = 0; j < ELEMS; ++j)
        nv[j] = vsrc0[(size_t)(cg * CG + ci + 1) * HW + 256 * j];
    }
    int cl = ci & (GRP - 1);
    float nr = nS[cl][w], nc = nS[cl][128 + w];
    float4 c4 = *(const float4*)&c4S[cl][4 * w];
    const float* mc = &mrf[ci * 48];
    #pragma unroll
    for (int j = 0; j < ELEMS; ++j) {
      int r = r0 + 2 * j;
      float mR = mc[r], mC = mc[8 + r];
      float4 r4 = *(const float4*)&mc[16 + 4 * r];
      float sc = e2(mR * nr) * (r4.x + c4.x) + e2(mR * nc) * (r4.y + c4.y)
               + e2(mC * nr) * (r4.z + c4.z) + e2(mC * nc) * (r4.w + c4.w);
      smaxl = fmaxf(smaxl, sc);
      U[j] += sc * vr[j];
    }
    if (ci + 1 < CG) {
      #pragma unroll
      for (int j = 0; j < ELEMS; ++j) vr[j] = nv[j];
    }
  }
  float* zt = (cg == 0 ? out : ws + PZ_OFF) + (size_t)(b * CC + c0) * HW + base + tid;
  #pragma unroll
  for (int j = 0; j < ELEMS; ++j) zt[256 * j] = U[j];
  smaxl = blkmax4(smaxl);
  if (tid == 0) ws[BSX_OFF + bx] = smaxl;
}

// ---------------- K5: z combine+scale (512 blocks) + score recompute c0=31 (128 blocks) ----------------
#define K5_ZB (BC * 8)                 // 512
__global__ __launch_bounds__(256) void k5_final(float* __restrict__ out,
                                                const float* __restrict__ ws) {
  int bx = blockIdx.x;
  int tid = threadIdx.x;
  if (bx < K5_ZB) {
    int p = bx >> 3, sub = bx & 7;     // p = b*CC + c0 z-plane
    int c0 = p & (CC - 1);
    __shared__ float sm;
    if (tid < 64) {
      float a = (tid < 48) ? ws[BSX_OFF + c0 * 48 + tid] : 0.f;
      #pragma unroll
      for (int o = 1; o < 64; o <<= 1) a = fmaxf(a, __shfl_xor(a, o, 64));
      if (tid == 0) sm = a;
    }
    __syncthreads();
    float ism = rcpf(sm);
    const float* pz = ws + PZ_OFF;
    int off = p * HW + sub * 1536 + tid;
    #pragma unroll
    for (int j = 0; j < 6; ++j) {
      int i = off + 256 * j;
      out[i] = (out[i] + pz[i]) * ism;
    }
  } else {
    int sp = bx - K5_ZB;               // 128 blocks: plane = sp>>1, half = sp&1
    int plane = sp >> 1, half = sp & 1;
    const float* rec = ws + REC_OFF + (size_t)((CC - 1) * BC + plane) * RECSZ;
    __shared__ __align__(16) float R[RECSZ];
    __shared__ float s44[4][4];
    __shared__ float sm;
    for (int i = tid; i < RECSZ / 4; i += 256) ((float4*)R)[i] = ((const float4*)rec)[i];
    float bm = ws[BMX_OFF + (CC - 1) * 256 + tid];
    #pragma unroll
    for (int o = 4; o <= 32; o <<= 1) bm = fmaxf(bm, __shfl_xor(bm, o, 64));
    if ((tid & 63) < 4) s44[tid >> 6][tid & 3] = bm;
    if (tid < 64) {
      float a = (tid < 48) ? ws[BSX_OFF + (CC - 1) * 48 + tid] : 0.f;
      #pragma unroll
      for (int o = 1; o < 64; o <<= 1) a = fmaxf(a, __shfl_xor(a, o, 64));
      if (tid == 0) sm = a;
    }
    __syncthreads();
    float im0 = rcpf(fmaxf(fmaxf(s44[0][0], s44[1][0]), fmaxf(s44[2][0], s44[3][0])));
    float im1 = rcpf(fmaxf(fmaxf(s44[0][1], s44[1][1]), fmaxf(s44[2][1], s44[3][1])));
    float im2 = rcpf(fmaxf(fmaxf(s44[0][2], s44[1][2]), fmaxf(s44[2][2], s44[3][2])));
    float im3 = rcpf(fmaxf(fmaxf(s44[0][3], s44[1][3]), fmaxf(s44[2][3], s44[3][3])));
    float isml = rcpf(sm);
    float* sout = out + (size_t)NPLANE + (size_t)plane * HW + half * 6144;
    #pragma unroll 4
    for (int e = tid; e < 6144; e += 256) {
      int idx = half * 6144 + e;
      int h = idx >> 7, ww = idx & 127;
      float mR = R[h], mC = R[96 + h];
      float nr = R[192 + ww], nc = R[320 + ww];
      float4 r4 = *(const float4*)&R[448 + 4 * h];
      float4 c4 = *(const float4*)&R[832 + 4 * ww];
      float A0 = c4.x * im0, A1 = c4.y * im1, A2 = c4.z * im2, A3 = c4.w * im3;
      float sc = e2(mR * nr) * fmaf(r4.x, im0, A0) + e2(mR * nc) * fmaf(r4.y, im1, A1)
               + e2(mC * nr) * fmaf(r4.z, im2, A2) + e2(mC * nc) * fmaf(r4.w, im3, A3);
      sout[e] = sc * isml;
    }
  }
}

extern "C" void kernel_launch(void* const* d_in, const int* in_sizes, int n_in,
                              void* d_out, int out_size, void* d_ws, size_t ws_size,
                              hipStream_t stream) {
  const float* q = (const float*)d_in[0];
  const float* k = (const float*)d_in[1];
  const float* v = (const float*)d_in[2];
  float* out = (float*)d_out;
  float* ws = (float*)d_ws;
  k1_plane_sums<<<2 * BC, 256, 0, stream>>>(q, k, ws);
  k2_vec_norm<<<CC * 4, 256, 0, stream>>>(ws);
  k3_rc<<<CC * BC * 4, 256, 0, stream>>>(ws);
  k4_score<<<CC * BB * TILES * NCG, 256, 0, stream>>>(v, ws, out);
  k5_final<<<K5_ZB + 128, 256, 0, stream>>>(out, ws);
}